// Round 6
// baseline (811.585 us; speedup 1.0000x reference)
//
#include <hip/hip_runtime.h>

#define S_LEN 920
#define DMODEL 1536
#define NH 4
#define HD 384
#define LREL 1839
#define BATCH 8
#define MTOT (BATCH * S_LEN)   // 7360
#define KPAD 960               // Vt column stride (keys, padded)
#define NBH (BATCH * NH)       // 32

// ---- ws layout (bytes), total 124,630,272 (ws_size >= 187.5 MB inferred) ----
// Xb [0, 22,609,920) and Wt [22,609,920, 36,765,696) are dead after qkv;
// Tp (full, 32 bh) aliases them and extends beyond.
#define TP_OFF   0UL            // 32*920*920*2 = 54,169,600
#define SMAX_OFF 54169600UL     // 32*920*4     =    117,760
#define SSUM_OFF 54287360UL     // 32*920*4     =    117,760
#define EB_OFF   54405120UL     // 1839*384*2   =  1,412,352
#define QB_OFF   55817472UL     // 7360*1536*2  = 22,609,920
#define KB_OFF   78427392UL     // 7360*1536*2  = 22,609,920
#define VT_OFF   101037312UL    // 32*384*960*2 = 23,592,960

typedef __attribute__((ext_vector_type(8))) short  s16x8;
typedef __attribute__((ext_vector_type(4))) short  s16x4;
typedef __attribute__((ext_vector_type(8))) __bf16 bf16x8;
typedef __attribute__((ext_vector_type(4))) float  f32x4;

__device__ __forceinline__ short f2b(float x) {
  unsigned u = __builtin_bit_cast(unsigned, x);
  unsigned r = (u + 0x7FFFu + ((u >> 16) & 1u)) >> 16;
  return (short)r;
}
__device__ __forceinline__ float b2f(short s) {
  unsigned u = ((unsigned)(unsigned short)s) << 16;
  return __builtin_bit_cast(float, u);
}

__device__ __forceinline__ void load_lds16(const short* g, short* lds) {
  __builtin_amdgcn_global_load_lds(
      (const __attribute__((address_space(1))) void*)g,
      (__attribute__((address_space(3))) void*)lds, 16, 0, 0);
}

__device__ __forceinline__ f32x4 mfma_bf16(s16x8 a, s16x8 b, f32x4 c) {
  return __builtin_amdgcn_mfma_f32_16x16x32_bf16(
      __builtin_bit_cast(bf16x8, a), __builtin_bit_cast(bf16x8, b), c, 0, 0, 0);
}

// ---------------------------------------------------------------------------
// 128x128 tile GEMM, C = A * B(NxK row-major)^T.  K multiple of 64.
// acc[i][j][r] = C[m0+wm+i*16+(lane>>4)*4+r][n0+wn+j*16+(lane&15)]
// ---------------------------------------------------------------------------
__device__ __forceinline__ void gemm_core(short* As, short* Bs,
                                          const short* __restrict__ A, int ldA, int mClamp,
                                          const short* __restrict__ B, int ldB, int nClamp,
                                          int K, int m0, int n0, f32x4 acc[4][4]) {
  const int tid  = threadIdx.x;
  const int w    = tid >> 6;
  const int lane = tid & 63;
  const int lrow = lane >> 3;
  const int lcol = (lane & 7) * 8;
  const int lr   = lane & 15;
  const int lq   = lane >> 4;
  const int wm   = (w >> 1) * 64;
  const int wn   = (w & 1) * 64;

  const short* pa[4];
  const short* pb[4];
  short* la[4];
  short* lb[4];
#pragma unroll
  for (int i = 0; i < 4; ++i) {
    int row = w * 32 + i * 8 + lrow;
    int ra = m0 + row; if (ra > mClamp) ra = mClamp;
    int rb = n0 + row; if (rb > nClamp) rb = nClamp;
    pa[i] = A + (size_t)ra * ldA + lcol;
    pb[i] = B + (size_t)rb * ldB + lcol;
    la[i] = &As[(w * 32 + i * 8) * 64];
    lb[i] = &Bs[(w * 32 + i * 8) * 64];
  }

#pragma unroll
  for (int i = 0; i < 4; ++i)
#pragma unroll
    for (int j = 0; j < 4; ++j) acc[i][j] = (f32x4){0.f, 0.f, 0.f, 0.f};

  for (int k0 = 0; k0 < K; k0 += 64) {
#pragma unroll
    for (int i = 0; i < 4; ++i) {
      load_lds16(pa[i] + k0, la[i]);
      load_lds16(pb[i] + k0, lb[i]);
    }
    __syncthreads();
#pragma unroll
    for (int kk = 0; kk < 2; ++kk) {
      s16x8 af[4], bf[4];
#pragma unroll
      for (int f = 0; f < 4; ++f)
        af[f] = *(const s16x8*)&As[(wm + f * 16 + lr) * 64 + kk * 32 + lq * 8];
#pragma unroll
      for (int f = 0; f < 4; ++f)
        bf[f] = *(const s16x8*)&Bs[(wn + f * 16 + lr) * 64 + kk * 32 + lq * 8];
#pragma unroll
      for (int i = 0; i < 4; ++i)
#pragma unroll
        for (int j = 0; j < 4; ++j)
          acc[i][j] = mfma_bf16(af[i], bf[j], acc[i][j]);
    }
    __syncthreads();
  }
}

// ---------------------------------------------------------------------------
// 128x256 tile GEMM.  As: 128*64 shorts, Bs: 256*64 shorts.
// acc[i][j][r] = C[m0+(w>>1)*64+i*16+(lane>>4)*4+r][n0+(w&1)*128+j*16+(lane&15)]
// ---------------------------------------------------------------------------
__device__ __forceinline__ void gemm_core256(short* As, short* Bs,
                                             const short* __restrict__ A, int ldA, int mClamp,
                                             const short* __restrict__ B, int ldB, int nClamp,
                                             int K, int m0, int n0, f32x4 acc[4][8]) {
  const int tid  = threadIdx.x;
  const int w    = tid >> 6;
  const int lane = tid & 63;
  const int lrow = lane >> 3;
  const int lcol = (lane & 7) * 8;
  const int lr   = lane & 15;
  const int lq   = lane >> 4;
  const int wm   = (w >> 1) * 64;
  const int wn   = (w & 1) * 128;

  const short* pa[4];
  short* la[4];
  const short* pb[8];
  short* lb[8];
#pragma unroll
  for (int i = 0; i < 4; ++i) {
    int row = w * 32 + i * 8 + lrow;
    int ra = m0 + row; if (ra > mClamp) ra = mClamp;
    pa[i] = A + (size_t)ra * ldA + lcol;
    la[i] = &As[(w * 32 + i * 8) * 64];
  }
#pragma unroll
  for (int i = 0; i < 8; ++i) {
    int row = w * 64 + i * 8 + lrow;
    int rb = n0 + row; if (rb > nClamp) rb = nClamp;
    pb[i] = B + (size_t)rb * ldB + lcol;
    lb[i] = &Bs[(w * 64 + i * 8) * 64];
  }

#pragma unroll
  for (int i = 0; i < 4; ++i)
#pragma unroll
    for (int j = 0; j < 8; ++j) acc[i][j] = (f32x4){0.f, 0.f, 0.f, 0.f};

  for (int k0 = 0; k0 < K; k0 += 64) {
#pragma unroll
    for (int i = 0; i < 4; ++i) load_lds16(pa[i] + k0, la[i]);
#pragma unroll
    for (int i = 0; i < 8; ++i) load_lds16(pb[i] + k0, lb[i]);
    __syncthreads();
#pragma unroll
    for (int kk = 0; kk < 2; ++kk) {
      s16x8 af[4], bf[8];
#pragma unroll
      for (int f = 0; f < 4; ++f)
        af[f] = *(const s16x8*)&As[(wm + f * 16 + lr) * 64 + kk * 32 + lq * 8];
#pragma unroll
      for (int f = 0; f < 8; ++f)
        bf[f] = *(const s16x8*)&Bs[(wn + f * 16 + lr) * 64 + kk * 32 + lq * 8];
#pragma unroll
      for (int i = 0; i < 4; ++i)
#pragma unroll
        for (int j = 0; j < 8; ++j)
          acc[i][j] = mfma_bf16(af[i], bf[j], acc[i][j]);
    }
    __syncthreads();
  }
}

// ---------------------------------------------------------------------------
__global__ void k_cast(const float* __restrict__ X, short* __restrict__ O, int n4) {
  int i = blockIdx.x * blockDim.x + threadIdx.x;
  if (i >= n4) return;
  float4 v = ((const float4*)X)[i];
  s16x4 o = {f2b(v.x), f2b(v.y), f2b(v.z), f2b(v.w)};
  *(s16x4*)&O[(size_t)i * 4] = o;
}

__global__ void k_transpose_w(const float* __restrict__ W0, const float* __restrict__ W1,
                              const float* __restrict__ W2, short* __restrict__ Wt) {
  const float* W = (blockIdx.z == 0) ? W0 : ((blockIdx.z == 1) ? W1 : W2);
  short* O = Wt + (size_t)blockIdx.z * DMODEL * DMODEL;
  __shared__ float t[32][33];
  int tx = threadIdx.x, ty = threadIdx.y;
  int n0 = blockIdx.x * 32, k0 = blockIdx.y * 32;
#pragma unroll
  for (int i = 0; i < 4; ++i)
    t[ty + i * 8][tx] = W[(size_t)(k0 + ty + i * 8) * DMODEL + n0 + tx];
  __syncthreads();
#pragma unroll
  for (int i = 0; i < 4; ++i)
    O[(size_t)(n0 + ty + i * 8) * DMODEL + k0 + tx] = f2b(t[tx][ty + i * 8]);
}

// ---------------------------------------------------------------------------
// QKV: 128x256 tiles, grid (348,1,3), XCD-swizzled (t%8 = XCD).
__global__ __launch_bounds__(256, 2) void k_gemm_qkv(const short* __restrict__ Xb,
                                                     const short* __restrict__ Wt,
                                                     short* __restrict__ Qb,
                                                     short* __restrict__ Kb,
                                                     short* __restrict__ Vt) {
  __shared__ short smem[24576];
  const int z = blockIdx.z;
  int t = blockIdx.x;
  int m_idx, n_idx;
  if (t < 336) { int band = t / 48, loc = t - band * 48;
                 m_idx = band * 8 + (loc & 7); n_idx = loc >> 3; }
  else         { int u = t - 336; m_idx = 56 + (u & 1); n_idx = u >> 1; }
  const int m0 = m_idx * 128, n0 = n_idx * 256;

  f32x4 acc[4][8];
  gemm_core256(smem, smem + 8192, Xb, DMODEL, MTOT - 1,
               Wt + (size_t)z * DMODEL * DMODEL, DMODEL, DMODEL - 1,
               DMODEL, m0, n0, acc);

  const int tid = threadIdx.x, w = tid >> 6, lane = tid & 63;
  const int lr = lane & 15, lq = lane >> 4;
  const int wm = (w >> 1) * 64, wn = (w & 1) * 128;

  if (z == 2) {
    // transpose each 128-wide n-half through LDS (stride 132), store Vt rows.
    short* T16 = smem;
    const int m_local_s = tid & 127, h2 = tid >> 7;
    for (int half = 0; half < 2; ++half) {
      if ((w & 1) == half) {
#pragma unroll
        for (int i = 0; i < 4; ++i)
#pragma unroll
          for (int j = 0; j < 8; ++j) {
            int nl = j * 16 + lr;
#pragma unroll
            for (int r = 0; r < 4; ++r)
              T16[nl * 132 + wm + i * 16 + lq * 4 + r] = f2b(acc[i][j][r]);
          }
      }
      __syncthreads();
      const int m = m0 + m_local_s;
      if (m < MTOT) {
        const int b = m / S_LEN, s = m - b * S_LEN;
        for (int p = 0; p < 64; ++p) {
          int nl = p * 2 + h2;
          int n = n0 + half * 128 + nl;
          int h = n / HD, d = n - h * HD;
          Vt[(((size_t)(b * NH + h)) * HD + d) * KPAD + s] = T16[nl * 132 + m_local_s];
        }
      }
      __syncthreads();
    }
  } else {
    const float inv = 0.05103103630798287f;  // 1/sqrt(384)
    short* dstb = (z == 0) ? Qb : Kb;
#pragma unroll
    for (int i = 0; i < 4; ++i)
#pragma unroll
      for (int j = 0; j < 8; ++j) {
        int n = n0 + wn + j * 16 + lr;
#pragma unroll
        for (int r = 0; r < 4; ++r) {
          int m = m0 + wm + i * 16 + lq * 4 + r;
          if (m >= MTOT) continue;
          float v = acc[i][j][r];
          dstb[(size_t)m * DMODEL + n] = f2b(z == 0 ? v * inv : v);
        }
      }
  }
}

// T = Q @ E^T stored PACKED: Tp[m][n] = dot(E[n-m+919], Q[m]).  Band tiles
// 6 <= i+j <= 14 only.  Grid (71,1,32).
__global__ __launch_bounds__(256) void k_gemm_T(const short* __restrict__ Qb,
                                                const short* __restrict__ Eb,
                                                short* __restrict__ Tp) {
  __shared__ short smem[16384];
  const int bh = blockIdx.z, b = bh >> 2, h = bh & 3;
  int t = blockIdx.x;
  int i_idx, j_idx;
  if (t < 7) { i_idx = t; j_idx = 6 - t; }
  else { int u = t - 7; int s = 7 + (u >> 3); i_idx = u & 7; j_idx = s - i_idx; }
  const int m0 = i_idx * 128, n0 = j_idx * 128;
  const short* A = Qb + (size_t)b * S_LEN * DMODEL + h * HD;
  f32x4 acc[4][4];
  gemm_core(smem, smem + 8192, A, DMODEL, S_LEN - 1, Eb, HD, LREL - 1, HD, m0, n0, acc);
  const int tid = threadIdx.x, w = tid >> 6, lane = tid & 63;
  const int lr = lane & 15, lq = lane >> 4;
  const int wm = (w >> 1) * 64, wn = (w & 1) * 64;
#pragma unroll
  for (int i = 0; i < 4; ++i)
#pragma unroll
    for (int j = 0; j < 4; ++j) {
      int l = n0 + wn + j * 16 + lr;           // rel-pos index
#pragma unroll
      for (int r = 0; r < 4; ++r) {
        int m = m0 + wm + i * 16 + lq * 4 + r;
        if (m < S_LEN) {
          int jp = l - (S_LEN - 1) + m;        // key index
          if (jp >= 0 && jp < S_LEN)
            Tp[((size_t)bh * S_LEN + m) * S_LEN + jp] = f2b(acc[i][j][r]);
        }
      }
    }
}

// ---------------------------------------------------------------------------
// Pass A: exact softmax stats (row max, row sum of exp) for 64 q-rows/block.
// Grid dim3(15, 32).  S = Q K^T + Tp, cols >= 920 masked.
// Wave w covers cols w*32..w*32+31 of each 128-key tile.
__global__ __launch_bounds__(256) void k_stats(const short* __restrict__ Qb,
                                               const short* __restrict__ Kb,
                                               const short* __restrict__ Tp,
                                               float* __restrict__ smax,
                                               float* __restrict__ ssum) {
  __shared__ short Qs[64 * 64];
  __shared__ short Ks[128 * 64];
  __shared__ float redm[4][64];
  __shared__ float reds[4][64];
  __shared__ float run_m[64], run_l[64], newm[64];
  const int bh = blockIdx.y, b = bh >> 2, h = bh & 3;
  const int m0 = blockIdx.x * 64;
  const int tid = threadIdx.x, w = tid >> 6, lane = tid & 63;
  const int lrow = lane >> 3, lcol = (lane & 7) * 8, lr = lane & 15, lq = lane >> 4;
  const short* Qp = Qb + (size_t)b * S_LEN * DMODEL + h * HD;
  const short* Kp = Kb + (size_t)b * S_LEN * DMODEL + h * HD;

  if (tid < 64) { run_m[tid] = -1e30f; run_l[tid] = 0.f; }

  const short* qa[2];
  short* ql[2];
#pragma unroll
  for (int f = 0; f < 2; ++f) {
    int row = w * 16 + f * 8 + lrow;
    int gr = m0 + row; if (gr > S_LEN - 1) gr = S_LEN - 1;
    qa[f] = Qp + (size_t)gr * DMODEL + lcol;
    ql[f] = &Qs[row * 64];
  }

  for (int kt = 0; kt < 8; ++kt) {
    f32x4 acc[4][2];
#pragma unroll
    for (int i = 0; i < 4; ++i) {
      acc[i][0] = (f32x4){0.f, 0.f, 0.f, 0.f};
      acc[i][1] = (f32x4){0.f, 0.f, 0.f, 0.f};
    }
    for (int d0 = 0; d0 < HD; d0 += 64) {
#pragma unroll
      for (int f = 0; f < 2; ++f) load_lds16(qa[f] + d0, ql[f]);
#pragma unroll
      for (int f = 0; f < 4; ++f) {
        int row = w * 32 + f * 8 + lrow;
        int gr = kt * 128 + row; if (gr > S_LEN - 1) gr = S_LEN - 1;
        load_lds16(Kp + (size_t)gr * DMODEL + d0 + lcol, &Ks[row * 64]);
      }
      __syncthreads();
#pragma unroll
      for (int kk = 0; kk < 2; ++kk) {
        s16x8 af[4], bf[2];
#pragma unroll
        for (int i = 0; i < 4; ++i)
          af[i] = *(const s16x8*)&Qs[(i * 16 + lr) * 64 + kk * 32 + lq * 8];
#pragma unroll
        for (int j = 0; j < 2; ++j)
          bf[j] = *(const s16x8*)&Ks[(w * 32 + j * 16 + lr) * 64 + kk * 32 + lq * 8];
#pragma unroll
        for (int i = 0; i < 4; ++i)
#pragma unroll
          for (int j = 0; j < 2; ++j) acc[i][j] = mfma_bf16(af[i], bf[j], acc[i][j]);
      }
      __syncthreads();
    }
    // bias + mask
    float sv[4][2][4];
#pragma unroll
    for (int i = 0; i < 4; ++i)
#pragma unroll
      for (int j = 0; j < 2; ++j) {
        int col = kt * 128 + w * 32 + j * 16 + lr;
#pragma unroll
        for (int r = 0; r < 4; ++r) {
          int mrow = m0 + i * 16 + lq * 4 + r;
          float v = acc[i][j][r];
          if (col < S_LEN) {
            if (mrow < S_LEN)
              v += b2f(Tp[((size_t)bh * S_LEN + mrow) * S_LEN + col]);
          } else {
            v = -1e30f;
          }
          sv[i][j][r] = v;
        }
      }
    // tile row-max
#pragma unroll
    for (int i = 0; i < 4; ++i)
#pragma unroll
      for (int r = 0; r < 4; ++r) {
        float mx = fmaxf(sv[i][0][r], sv[i][1][r]);
        for (int msk = 1; msk < 16; msk <<= 1) mx = fmaxf(mx, __shfl_xor(mx, msk));
        if (lr == 0) redm[w][i * 16 + lq * 4 + r] = mx;
      }
    __syncthreads();
    if (tid < 64) {
      float tm = fmaxf(fmaxf(redm[0][tid], redm[1][tid]),
                       fmaxf(redm[2][tid], redm[3][tid]));
      float nm = fmaxf(run_m[tid], tm);
      run_l[tid] *= __expf(run_m[tid] - nm);
      run_m[tid] = nm;
      newm[tid] = nm;
    }
    __syncthreads();
    // tile row-sum of exp
#pragma unroll
    for (int i = 0; i < 4; ++i)
#pragma unroll
      for (int r = 0; r < 4; ++r) {
        float nm = newm[i * 16 + lq * 4 + r];
        float s = __expf(sv[i][0][r] - nm) + __expf(sv[i][1][r] - nm);
        for (int msk = 1; msk < 16; msk <<= 1) s += __shfl_xor(s, msk);
        if (lr == 0) reds[w][i * 16 + lq * 4 + r] = s;
      }
    __syncthreads();
    if (tid < 64) run_l[tid] += reds[0][tid] + reds[1][tid] + reds[2][tid] + reds[3][tid];
    __syncthreads();
  }
  if (tid < 64 && m0 + tid < S_LEN) {
    smax[bh * S_LEN + m0 + tid] = run_m[tid];
    ssum[bh * S_LEN + m0 + tid] = run_l[tid];
  }
}

// ---------------------------------------------------------------------------
// Pass B: fused P = exp(QK^T + Tp - max), O = P V, out = O / sum.
// Grid dim3(15, 32).  64 q-rows per block.  Wave w: QK cols w*32.., PV output
// cols (d) w*96..w*96+95.
__global__ __launch_bounds__(256) void k_ctx(const short* __restrict__ Qb,
                                             const short* __restrict__ Kb,
                                             const short* __restrict__ Tp,
                                             const short* __restrict__ Vt,
                                             const float* __restrict__ smax,
                                             const float* __restrict__ ssum,
                                             float* __restrict__ out) {
  __shared__ short SA[24576];      // QK phase: Qs[0,4096) Ks[4096,12288); PV: Vs[0,24576)
  __shared__ short Pl[64 * 128];
  __shared__ float rowm[64], rli[64];
  const int bh = blockIdx.y, b = bh >> 2, h = bh & 3;
  const int m0 = blockIdx.x * 64;
  const int tid = threadIdx.x, w = tid >> 6, lane = tid & 63;
  const int lrow = lane >> 3, lcol = (lane & 7) * 8, lr = lane & 15, lq = lane >> 4;
  const short* Qp = Qb + (size_t)b * S_LEN * DMODEL + h * HD;
  const short* Kp = Kb + (size_t)b * S_LEN * DMODEL + h * HD;
  const short* Vp = Vt + (size_t)bh * HD * KPAD;
  short* Qs = SA;
  short* Ks = SA + 4096;
  short* Vs = SA;

  if (tid < 64) {
    int m = m0 + tid;
    if (m < S_LEN) {
      rowm[tid] = smax[bh * S_LEN + m];
      rli[tid] = 1.0f / ssum[bh * S_LEN + m];
    } else {
      rowm[tid] = 0.f;
      rli[tid] = 0.f;
    }
  }

  f32x4 accO[4][6];
#pragma unroll
  for (int i = 0; i < 4; ++i)
#pragma unroll
    for (int jj = 0; jj < 6; ++jj) accO[i][jj] = (f32x4){0.f, 0.f, 0.f, 0.f};

  for (int kt = 0; kt < 8; ++kt) {
    f32x4 acc[4][2];
#pragma unroll
    for (int i = 0; i < 4; ++i) {
      acc[i][0] = (f32x4){0.f, 0.f, 0.f, 0.f};
      acc[i][1] = (f32x4){0.f, 0.f, 0.f, 0.f};
    }
    for (int d0 = 0; d0 < HD; d0 += 64) {
#pragma unroll
      for (int f = 0; f < 2; ++f) {
        int row = w * 16 + f * 8 + lrow;
        int gr = m0 + row; if (gr > S_LEN - 1) gr = S_LEN - 1;
        load_lds16(Qp + (size_t)gr * DMODEL + d0 + lcol, &Qs[row * 64]);
      }
#pragma unroll
      for (int f = 0; f < 4; ++f) {
        int row = w * 32 + f * 8 + lrow;
        int gr = kt * 128 + row; if (gr > S_LEN - 1) gr = S_LEN - 1;
        load_lds16(Kp + (size_t)gr * DMODEL + d0 + lcol, &Ks[row * 64]);
      }
      __syncthreads();
#pragma unroll
      for (int kk = 0; kk < 2; ++kk) {
        s16x8 af[4], bf[2];
#pragma unroll
        for (int i = 0; i < 4; ++i)
          af[i] = *(const s16x8*)&Qs[(i * 16 + lr) * 64 + kk * 32 + lq * 8];
#pragma unroll
        for (int j = 0; j < 2; ++j)
          bf[j] = *(const s16x8*)&Ks[(w * 32 + j * 16 + lr) * 64 + kk * 32 + lq * 8];
#pragma unroll
        for (int i = 0; i < 4; ++i)
#pragma unroll
          for (int j = 0; j < 2; ++j) acc[i][j] = mfma_bf16(af[i], bf[j], acc[i][j]);
      }
      __syncthreads();
    }
    // P = exp(S + bias - rowmax)  (bf16, unnormalized), masked cols -> 0
#pragma unroll
    for (int i = 0; i < 4; ++i)
#pragma unroll
      for (int j = 0; j < 2; ++j) {
        int col = kt * 128 + w * 32 + j * 16 + lr;
#pragma unroll
        for (int r = 0; r < 4; ++r) {
          int row = i * 16 + lq * 4 + r;
          int mrow = m0 + row;
          float e = 0.f;
          if (col < S_LEN) {
            float v = acc[i][j][r];
            if (mrow < S_LEN)
              v += b2f(Tp[((size_t)bh * S_LEN + mrow) * S_LEN + col]);
            e = __expf(v - rowm[row]);
          }
          Pl[row * 128 + w * 32 + j * 16 + lr] = f2b(e);
        }
      }
    __syncthreads();   // P complete; Qs/Ks dead -> Vs may overwrite
    const int nkc = (kt == 7) ? 1 : 2;   // keys >= 960 never needed (P==0)
    for (int kc = 0; kc < nkc; ++kc) {
#pragma unroll
      for (int f = 0; f < 12; ++f) {
        int row = w * 96 + f * 8 + lrow;          // d index 0..383
        load_lds16(Vp + (size_t)row * KPAD + kt * 128 + kc * 64 + lcol, &Vs[row * 64]);
      }
      __syncthreads();
#pragma unroll
      for (int kk = 0; kk < 2; ++kk) {
        s16x8 af[4], bf[6];
#pragma unroll
        for (int i = 0; i < 4; ++i)
          af[i] = *(const s16x8*)&Pl[(i * 16 + lr) * 128 + kc * 64 + kk * 32 + lq * 8];
#pragma unroll
        for (int jj = 0; jj < 6; ++jj)
          bf[jj] = *(const s16x8*)&Vs[(w * 96 + jj * 16 + lr) * 64 + kk * 32 + lq * 8];
#pragma unroll
        for (int i = 0; i < 4; ++i)
#pragma unroll
          for (int jj = 0; jj < 6; ++jj)
            accO[i][jj] = mfma_bf16(af[i], bf[jj], accO[i][jj]);
      }
      __syncthreads();
    }
  }
  // epilogue: out = O / rowsum
#pragma unroll
  for (int i = 0; i < 4; ++i)
#pragma unroll
    for (int jj = 0; jj < 6; ++jj) {
      int col = w * 96 + jj * 16 + lr;            // 0..383
#pragma unroll
      for (int r = 0; r < 4; ++r) {
        int row = i * 16 + lq * 4 + r;
        int m = m0 + row;
        if (m < S_LEN)
          out[((size_t)b * S_LEN + m) * DMODEL + h * HD + col] =
              accO[i][jj][r] * rli[row];
      }
    }
}

// ---------------------------------------------------------------------------
extern "C" void kernel_launch(void* const* d_in, const int* in_sizes, int n_in,
                              void* d_out, int out_size, void* d_ws, size_t ws_size,
                              hipStream_t stream) {
  const float* hs = (const float*)d_in[0];
  const float* wq = (const float*)d_in[1];
  const float* wk = (const float*)d_in[2];
  const float* wv = (const float*)d_in[3];
  const float* de = (const float*)d_in[4];
  char* ws = (char*)d_ws;

  short* Xb   = (short*)(ws + 0);
  short* Wt   = (short*)(ws + 22609920UL);
  short* Tp   = (short*)(ws + TP_OFF);     // aliases Xb/Wt (dead after qkv)
  float* smax = (float*)(ws + SMAX_OFF);
  float* ssum = (float*)(ws + SSUM_OFF);
  short* Eb   = (short*)(ws + EB_OFF);
  short* Qb   = (short*)(ws + QB_OFF);
  short* Kb   = (short*)(ws + KB_OFF);
  short* Vt   = (short*)(ws + VT_OFF);

  k_cast<<<(MTOT * DMODEL / 4 + 255) / 256, 256, 0, stream>>>(hs, Xb, MTOT * DMODEL / 4);
  k_cast<<<(LREL * HD / 4 + 255) / 256, 256, 0, stream>>>(de, Eb, LREL * HD / 4);
  k_transpose_w<<<dim3(48, 48, 3), dim3(32, 8, 1), 0, stream>>>(wq, wk, wv, Wt);

  k_gemm_qkv<<<dim3(348, 1, 3), 256, 0, stream>>>(Xb, Wt, Qb, Kb, Vt);

  k_gemm_T<<<dim3(71, 1, NBH), 256, 0, stream>>>(Qb, Eb, Tp);
  k_stats<<<dim3(15, NBH), 256, 0, stream>>>(Qb, Kb, Tp, smax, ssum);
  k_ctx<<<dim3(15, NBH), 256, 0, stream>>>(Qb, Kb, Tp, Vt, smax, ssum, (float*)d_out);
}